// Round 1
// baseline (1938.890 us; speedup 1.0000x reference)
//
#include <hip/hip_runtime.h>
#include <hip/hip_bf16.h>
#include <stdint.h>

// Problem constants (fixed by setup_inputs; npoint/k scalars arrive as d_in[8]/d_in[9]
// but are compile-time constants of the problem).
#define BB   16
#define NN   4096
#define NP   1024
#define KK   32
#define CP   64
#define CIN  67    // 3 + 64
#define H3   128

// ---------- exact-rounding helpers (match numpy op-by-op; no fma contraction) ----------
__device__ __forceinline__ float sq3_exact(float x, float y, float z) {
#pragma clang fp contract(off)
    float a = x * x;
    float b = y * y;
    float c = z * z;
    return (a + b) + c;
}
__device__ __forceinline__ float dot3_exact(float ax, float ay, float az,
                                            float bx, float by, float bz) {
#pragma clang fp contract(off)
    float a = ax * bx;
    float b = ay * by;
    float c = az * bz;
    return (a + b) + c;
}
__device__ __forceinline__ float d2_exact(float sn, float sx, float dt) {
#pragma clang fp contract(off)
    return (sn + sx) - 2.0f * dt;   // 2*dt is exact; matches (a+b) - 2*dot
}
__device__ __forceinline__ uint32_t f32_sortable(float f) {
    uint32_t u = __float_as_uint(f);
    return (u & 0x80000000u) ? ~u : (u | 0x80000000u);
}
__device__ __forceinline__ unsigned long long umin64(unsigned long long a, unsigned long long b) {
    return a < b ? a : b;
}

// ---------- kernel 1: transpose points (B,Cp,N) -> bf16 (B,N,Cp) for coalesced gathers ----------
__global__ void __launch_bounds__(256) transpose_pts(const float* __restrict__ pts,
                                                     __hip_bfloat16* __restrict__ ptsT) {
    __shared__ float tile[64][65];
    int b  = blockIdx.y;
    int n0 = blockIdx.x * 64;
    int tx = threadIdx.x & 63, ty = threadIdx.x >> 6;   // 64 x 4
    const float* src = pts + (size_t)b * CP * NN;
    for (int c = ty; c < 64; c += 4)
        tile[c][tx] = src[c * NN + n0 + tx];
    __syncthreads();
    __hip_bfloat16* dst = ptsT + ((size_t)b * NN + n0) * CP;
    for (int nn2 = ty; nn2 < 64; nn2 += 4)
        dst[nn2 * CP + tx] = __float2bfloat16(tile[tx][nn2]);
}

// ---------- kernel 2: FPS, one block per batch; writes new_xyz (output 0) ----------
// Serial 1024-iteration chain: dist_min update (exact rounding) + block argmax
// (ties -> smallest index, matching jnp.argmax). One barrier/iter via parity buffers.
__global__ void __launch_bounds__(256) fps_kernel(const float* __restrict__ xyz,
                                                  float* __restrict__ newxyz) {
    __shared__ float sxs[NN], sys_[NN], szs[NN];     // 48 KB copy for centroid lookup
    __shared__ float bval[2][4];
    __shared__ int   bidx[2][4];
    int b = blockIdx.x;
    int tid = threadIdx.x;
    const float* xb = xyz + (size_t)b * NN * 3;
    float px[16], py[16], pz[16], dmin[16];
#pragma unroll
    for (int j = 0; j < 16; j++) {
        int n = j * 256 + tid;
        float x = xb[n * 3 + 0], y = xb[n * 3 + 1], z = xb[n * 3 + 2];
        px[j] = x; py[j] = y; pz[j] = z;
        sxs[n] = x; sys_[n] = y; szs[n] = z;
        dmin[j] = 1e10f;                              // matches 10000000000.0 init
    }
    __syncthreads();
    int far = 0;                                      // cents[0] = 0
    float* nxb = newxyz + (size_t)b * NP * 3;
    for (int t = 0; t < NP; t++) {
        float cx = sxs[far], cy = sys_[far], cz = szs[far];
        if (tid < 3) nxb[t * 3 + tid] = (tid == 0) ? cx : ((tid == 1) ? cy : cz);
        if (t == NP - 1) break;                       // last argmax unused by reference
        float bv = -1.0f; int bi = 0;
#pragma unroll
        for (int j = 0; j < 16; j++) {
            float dx = px[j] - cx, dy = py[j] - cy, dz = pz[j] - cz;
            float s = sq3_exact(dx, dy, dz);
            float d = fminf(dmin[j], s);
            dmin[j] = d;
            bi = (d > bv) ? (j * 256 + tid) : bi;     // strict > : earlier (smaller) idx wins ties
            bv = fmaxf(bv, d);
        }
#pragma unroll
        for (int off = 32; off > 0; off >>= 1) {
            float ov = __shfl_xor(bv, off);
            int   oi = __shfl_xor(bi, off);
            bool take = (ov > bv) || ((ov == bv) && (oi < bi));
            bv = take ? ov : bv;
            bi = take ? oi : bi;
        }
        int par = t & 1;
        if ((tid & 63) == 0) { bval[par][tid >> 6] = bv; bidx[par][tid >> 6] = bi; }
        __syncthreads();
        bv = bval[par][0]; bi = bidx[par][0];
#pragma unroll
        for (int q = 1; q < 4; q++) {
            float ov = bval[par][q]; int oi = bidx[par][q];
            bool take = (ov > bv) || ((ov == bv) && (oi < bi));
            bv = take ? ov : bv; bi = take ? oi : bi;
        }
        far = bi;
    }
}

// ---------- kernel 3: exact kNN (top-32 smallest (d2, idx) lexicographic = lax.top_k set) ----------
// One block per centroid. Keys u64 = (sortable(d2) << 32) | n : unique, total order.
// 32 extraction rounds of block-wide min.
__global__ void __launch_bounds__(256) knn_kernel(const float* __restrict__ xyz,
                                                  const float* __restrict__ newxyz,
                                                  unsigned short* __restrict__ knn_out) {
    __shared__ unsigned long long wmin[2][4];
    int s = blockIdx.x, b = blockIdx.y, tid = threadIdx.x;
    const float* c3 = newxyz + ((size_t)b * NP + s) * 3;
    float cx = c3[0], cy = c3[1], cz = c3[2];
    float sn = sq3_exact(cx, cy, cz);
    const float* xb = xyz + (size_t)b * NN * 3;
    unsigned long long key[16], mymin = ~0ull;
#pragma unroll
    for (int j = 0; j < 16; j++) {
        int n = j * 256 + tid;
        float x = xb[n * 3 + 0], y = xb[n * 3 + 1], z = xb[n * 3 + 2];
        float sx = sq3_exact(x, y, z);
        float dt = dot3_exact(cx, cy, cz, x, y, z);
        float d2 = d2_exact(sn, sx, dt);
        unsigned long long kk = ((unsigned long long)f32_sortable(d2) << 32) | (unsigned)n;
        key[j] = kk;
        mymin = umin64(mymin, kk);
    }
    unsigned short* out = knn_out + ((size_t)b * NP + s) * KK;
    for (int r = 0; r < KK; r++) {
        unsigned long long m = mymin;
#pragma unroll
        for (int off = 32; off > 0; off >>= 1) {
            unsigned long long om = __shfl_xor(m, off);
            m = umin64(m, om);
        }
        int par = r & 1;
        if ((tid & 63) == 0) wmin[par][tid >> 6] = m;
        __syncthreads();
        m = umin64(umin64(wmin[par][0], wmin[par][1]),
                   umin64(wmin[par][2], wmin[par][3]));
        int n = (int)(uint32_t)m;                       // low 32 bits hold the index
        if (tid == 0) out[r] = (unsigned short)n;
        if (tid == (n & 255)) {                         // owner invalidates + recomputes its min
            key[n >> 8] = ~0ull;
            unsigned long long mm = ~0ull;
#pragma unroll
            for (int j = 0; j < 16; j++) mm = umin64(mm, key[j]);
            mymin = mm;
        }
    }
}

// ---------- kernel 4: gather + 3-layer MLP + maxpool over k (fp32 vector FMA) ----------
// One block per (b,s). LDS: weight buffer reused per layer; activations stored
// transposed [channel][k] (stride 36: keeps float4 16B alignment, mod-32 != 0).
__global__ void __launch_bounds__(256) mlp_kernel(const float* __restrict__ xyz,
                                                  const __hip_bfloat16* __restrict__ ptsT,
                                                  const unsigned short* __restrict__ knn_idx,
                                                  const float* __restrict__ W1, const float* __restrict__ b1,
                                                  const float* __restrict__ W2, const float* __restrict__ b2,
                                                  const float* __restrict__ W3, const float* __restrict__ b3,
                                                  float* __restrict__ out_np) {
    __shared__ __attribute__((aligned(16))) float Wl[128 * 65];   // 33.3 KB, stride 67 (L1) / 65 (L2,L3)
    __shared__ __attribute__((aligned(16))) float gt [CIN * 36];  // grouped  [c][k]
    __shared__ __attribute__((aligned(16))) float h1t[64 * 36];   // h1       [c][k]
    __shared__ __attribute__((aligned(16))) float h2t[64 * 36];   // h2       [c][k]
    __shared__ int   nidx[KK];
    __shared__ float pmax[256];
    int s = blockIdx.x, b = blockIdx.y, tid = threadIdx.x;

    if (tid < KK) nidx[tid] = (int)knn_idx[((size_t)b * NP + s) * KK + tid];
    for (int i = tid; i < 64 * 67; i += 256) Wl[i] = W1[i];       // W1 row-major, stride 67
    __syncthreads();

    { // gather grouped features: c<3 -> xyz, else bf16 pointsT
        int k = tid >> 3, l8 = tid & 7;
        int n = nidx[k];
        const float* xp = xyz + ((size_t)b * NN + n) * 3;
        const __hip_bfloat16* pp = ptsT + ((size_t)b * NN + n) * CP;
        for (int c = l8; c < CIN; c += 8) {
            float v = (c < 3) ? xp[c] : __bfloat162float(pp[c - 3]);
            gt[c * 36 + k] = v;
        }
    }
    __syncthreads();

    const int o  = tid & 63;
    const int kq = tid >> 6;          // 4 groups of 8 k's
    { // ---- layer 1: 67 -> 64 ----
        float acc[8];
        float bias = b1[o];
#pragma unroll
        for (int i = 0; i < 8; i++) acc[i] = bias;
        for (int c = 0; c < CIN; c++) {
            float w = Wl[o * 67 + c];
            const float4* gp = (const float4*)&gt[c * 36 + (kq << 3)];
            float4 ga = gp[0], gb = gp[1];
            acc[0] = fmaf(w, ga.x, acc[0]); acc[1] = fmaf(w, ga.y, acc[1]);
            acc[2] = fmaf(w, ga.z, acc[2]); acc[3] = fmaf(w, ga.w, acc[3]);
            acc[4] = fmaf(w, gb.x, acc[4]); acc[5] = fmaf(w, gb.y, acc[5]);
            acc[6] = fmaf(w, gb.z, acc[6]); acc[7] = fmaf(w, gb.w, acc[7]);
        }
        float4 r0 = make_float4(fmaxf(acc[0], 0.f), fmaxf(acc[1], 0.f), fmaxf(acc[2], 0.f), fmaxf(acc[3], 0.f));
        float4 r1 = make_float4(fmaxf(acc[4], 0.f), fmaxf(acc[5], 0.f), fmaxf(acc[6], 0.f), fmaxf(acc[7], 0.f));
        *(float4*)&h1t[o * 36 + (kq << 3)]     = r0;
        *(float4*)&h1t[o * 36 + (kq << 3) + 4] = r1;
    }
    __syncthreads();
    for (int i = tid; i < 64 * 64; i += 256) Wl[(i >> 6) * 65 + (i & 63)] = W2[i];
    __syncthreads();
    { // ---- layer 2: 64 -> 64 ----
        float acc[8];
        float bias = b2[o];
#pragma unroll
        for (int i = 0; i < 8; i++) acc[i] = bias;
        for (int c = 0; c < 64; c++) {
            float w = Wl[o * 65 + c];
            const float4* gp = (const float4*)&h1t[c * 36 + (kq << 3)];
            float4 ga = gp[0], gb = gp[1];
            acc[0] = fmaf(w, ga.x, acc[0]); acc[1] = fmaf(w, ga.y, acc[1]);
            acc[2] = fmaf(w, ga.z, acc[2]); acc[3] = fmaf(w, ga.w, acc[3]);
            acc[4] = fmaf(w, gb.x, acc[4]); acc[5] = fmaf(w, gb.y, acc[5]);
            acc[6] = fmaf(w, gb.z, acc[6]); acc[7] = fmaf(w, gb.w, acc[7]);
        }
        float4 r0 = make_float4(fmaxf(acc[0], 0.f), fmaxf(acc[1], 0.f), fmaxf(acc[2], 0.f), fmaxf(acc[3], 0.f));
        float4 r1 = make_float4(fmaxf(acc[4], 0.f), fmaxf(acc[5], 0.f), fmaxf(acc[6], 0.f), fmaxf(acc[7], 0.f));
        *(float4*)&h2t[o * 36 + (kq << 3)]     = r0;
        *(float4*)&h2t[o * 36 + (kq << 3) + 4] = r1;
    }
    __syncthreads();
    for (int i = tid; i < 128 * 64; i += 256) Wl[(i >> 6) * 65 + (i & 63)] = W3[i];
    __syncthreads();
    { // ---- layer 3: 64 -> 128, fused maxpool over 16 k's per thread ----
        const int o3 = tid & 127;
        const int kq3 = tid >> 7;     // 2 groups of 16 k's
        float acc[16];
        float bias = b3[o3];
#pragma unroll
        for (int i = 0; i < 16; i++) acc[i] = bias;
        for (int c = 0; c < 64; c++) {
            float w = Wl[o3 * 65 + c];
            const float4* hp = (const float4*)&h2t[c * 36 + (kq3 << 4)];
            float4 h0 = hp[0], h1v = hp[1], h2v = hp[2], h3v = hp[3];
            acc[0]  = fmaf(w, h0.x,  acc[0]);  acc[1]  = fmaf(w, h0.y,  acc[1]);
            acc[2]  = fmaf(w, h0.z,  acc[2]);  acc[3]  = fmaf(w, h0.w,  acc[3]);
            acc[4]  = fmaf(w, h1v.x, acc[4]);  acc[5]  = fmaf(w, h1v.y, acc[5]);
            acc[6]  = fmaf(w, h1v.z, acc[6]);  acc[7]  = fmaf(w, h1v.w, acc[7]);
            acc[8]  = fmaf(w, h2v.x, acc[8]);  acc[9]  = fmaf(w, h2v.y, acc[9]);
            acc[10] = fmaf(w, h2v.z, acc[10]); acc[11] = fmaf(w, h2v.w, acc[11]);
            acc[12] = fmaf(w, h3v.x, acc[12]); acc[13] = fmaf(w, h3v.y, acc[13]);
            acc[14] = fmaf(w, h3v.z, acc[14]); acc[15] = fmaf(w, h3v.w, acc[15]);
        }
        float m = acc[0];
#pragma unroll
        for (int i = 1; i < 16; i++) m = fmaxf(m, acc[i]);
        m = fmaxf(m, 0.0f);           // relu(max) == max(relu)
        pmax[tid] = m;
    }
    __syncthreads();
    if (tid < 128) {
        float m = fmaxf(pmax[tid], pmax[tid + 128]);
        out_np[((size_t)b * H3 + tid) * NP + s] = m;
    }
}

extern "C" void kernel_launch(void* const* d_in, const int* in_sizes, int n_in,
                              void* d_out, int out_size, void* d_ws, size_t ws_size,
                              hipStream_t stream) {
    (void)in_sizes; (void)n_in; (void)out_size; (void)ws_size;
    const float* xyz = (const float*)d_in[0];
    const float* pts = (const float*)d_in[1];
    const float* W1  = (const float*)d_in[2];
    const float* b1  = (const float*)d_in[3];
    const float* W2  = (const float*)d_in[4];
    const float* b2  = (const float*)d_in[5];
    const float* W3  = (const float*)d_in[6];
    const float* b3  = (const float*)d_in[7];

    float* out    = (float*)d_out;
    float* newxyz = out;                       // (B, NP, 3)
    float* newpts = out + (size_t)BB * NP * 3; // (B, 128, NP)

    // workspace: ptsT bf16 (8 MB) | knn_idx u16 (1 MB)
    __hip_bfloat16* ptsT = (__hip_bfloat16*)d_ws;
    unsigned short* knni = (unsigned short*)((char*)d_ws + (size_t)BB * NN * CP * sizeof(__hip_bfloat16));

    transpose_pts<<<dim3(NN / 64, BB), 256, 0, stream>>>(pts, ptsT);
    fps_kernel  <<<BB, 256, 0, stream>>>(xyz, newxyz);
    knn_kernel  <<<dim3(NP, BB), 256, 0, stream>>>(xyz, newxyz, knni);
    mlp_kernel  <<<dim3(NP, BB), 256, 0, stream>>>(xyz, ptsT, knni, W1, b1, W2, b2, W3, b3, newpts);
}

// Round 2
// 1722.213 us; speedup vs baseline: 1.1258x; 1.1258x over previous
//
#include <hip/hip_runtime.h>
#include <hip/hip_bf16.h>
#include <stdint.h>

// Problem constants (fixed by setup_inputs).
#define BB   16
#define NN   4096
#define NP   1024
#define KK   32
#define CP   64
#define CIN  67    // 3 + 64
#define H3   128

// ---------- exact-rounding helpers (match numpy op-by-op; no fma contraction) ----------
__device__ __forceinline__ float sq3_exact(float x, float y, float z) {
#pragma clang fp contract(off)
    float a = x * x;
    float b = y * y;
    float c = z * z;
    return (a + b) + c;
}
__device__ __forceinline__ float dot3_exact(float ax, float ay, float az,
                                            float bx, float by, float bz) {
#pragma clang fp contract(off)
    float a = ax * bx;
    float b = ay * by;
    float c = az * bz;
    return (a + b) + c;
}
__device__ __forceinline__ float d2_exact(float sn, float sx, float dt) {
#pragma clang fp contract(off)
    return (sn + sx) - 2.0f * dt;
}
__device__ __forceinline__ uint32_t f32_sortable(float f) {
    uint32_t u = __float_as_uint(f);
    return (u & 0x80000000u) ? ~u : (u | 0x80000000u);
}
__device__ __forceinline__ unsigned long long umin64(unsigned long long a, unsigned long long b) {
    return a < b ? a : b;
}
__device__ __forceinline__ unsigned long long umax64(unsigned long long a, unsigned long long b) {
    return a > b ? a : b;
}

// ---------- kernel 1: transpose points (B,Cp,N) -> bf16 (B,N,Cp) ----------
__global__ void __launch_bounds__(256) transpose_pts(const float* __restrict__ pts,
                                                     __hip_bfloat16* __restrict__ ptsT) {
    __shared__ float tile[64][65];
    int b  = blockIdx.y;
    int n0 = blockIdx.x * 64;
    int tx = threadIdx.x & 63, ty = threadIdx.x >> 6;   // 64 x 4
    const float* src = pts + (size_t)b * CP * NN;
    for (int c = ty; c < 64; c += 4)
        tile[c][tx] = src[c * NN + n0 + tx];
    __syncthreads();
    __hip_bfloat16* dst = ptsT + ((size_t)b * NN + n0) * CP;
    for (int nn2 = ty; nn2 < 64; nn2 += 4)
        dst[nn2 * CP + tx] = __float2bfloat16(tile[tx][nn2]);
}

// ---------- kernel 2: FPS, one block per batch ----------
// 512 threads, 8 pts/thread. Points pinned in VGPRs (asm barrier prevents the
// compiler rematerializing them from the LDS copy — R0's 68-VGPR kernel did
// exactly that, 48 ds_read_b32/thread/iter, 2.4x slowdown).
// Argmax via u64 key = (sortable(d)<<32) | (4095 - idx): umax == (max d, tie -> min idx),
// matching jnp.argmax. One barrier/iter via parity buffers.
#define FPS_T 512
#define FPS_J (NN / FPS_T)   // 8

__global__ void __launch_bounds__(FPS_T, 1) fps_kernel(const float* __restrict__ xyz,
                                                       float* __restrict__ newxyz) {
    __shared__ float sxs[NN], sys_[NN], szs[NN];   // 48 KB: centroid lookup + final writeback
    __shared__ int   farr[NP];
    __shared__ __attribute__((aligned(16))) unsigned long long kbuf[2][FPS_T / 64];
    int b = blockIdx.x;
    int tid = threadIdx.x;
    const float* xb = xyz + (size_t)b * NN * 3;
    float px[FPS_J], py[FPS_J], pz[FPS_J], dmin[FPS_J];
#pragma unroll
    for (int j = 0; j < FPS_J; j++) {
        int n = j * FPS_T + tid;
        float x = xb[n * 3 + 0], y = xb[n * 3 + 1], z = xb[n * 3 + 2];
        px[j] = x; py[j] = y; pz[j] = z;
        sxs[n] = x; sys_[n] = y; szs[n] = z;
        dmin[j] = 1e10f;                              // matches 10000000000.0 init
    }
#pragma unroll
    for (int j = 0; j < FPS_J; j++) {                 // pin to VGPRs: no LDS remat
        asm volatile("" : "+v"(px[j]), "+v"(py[j]), "+v"(pz[j]));
    }
    if (tid == 0) farr[0] = 0;                        // cents[0] = 0
    __syncthreads();
    int far = 0;
    for (int t = 0; t < NP - 1; t++) {
        float cx = sxs[far], cy = sys_[far], cz = szs[far];
        float bv = -1.0f; int bi = 0;
#pragma unroll
        for (int j = 0; j < FPS_J; j++) {
            float dx = px[j] - cx, dy = py[j] - cy, dz = pz[j] - cz;
            float s = sq3_exact(dx, dy, dz);
            float d = fminf(dmin[j], s);
            dmin[j] = d;
            bi = (d > bv) ? (j * FPS_T + tid) : bi;   // strict > : smaller idx wins ties
            bv = fmaxf(bv, d);
        }
        unsigned long long key =
            ((unsigned long long)f32_sortable(bv) << 32) | (unsigned)(NN - 1 - bi);
#pragma unroll
        for (int off = 32; off > 0; off >>= 1)
            key = umax64(key, __shfl_xor(key, off));
        int par = t & 1;
        if ((tid & 63) == 0) kbuf[par][tid >> 6] = key;
        __syncthreads();
        const ulonglong2* kp = (const ulonglong2*)kbuf[par];
        ulonglong2 k0 = kp[0], k1 = kp[1], k2 = kp[2], k3 = kp[3];
        unsigned long long m = umax64(umax64(k0.x, k0.y), umax64(k1.x, k1.y));
        m = umax64(m, umax64(umax64(k2.x, k2.y), umax64(k3.x, k3.y)));
        far = NN - 1 - (int)(unsigned)(m & 0xFFFFFFFFull);
        if (tid == 0) farr[t + 1] = far;
    }
    __syncthreads();
    float* nxb = newxyz + (size_t)b * NP * 3;
    for (int t = tid; t < NP; t += FPS_T) {
        int f = farr[t];
        nxb[t * 3 + 0] = sxs[f];
        nxb[t * 3 + 1] = sys_[f];
        nxb[t * 3 + 2] = szs[f];
    }
}

// ---------- kernel 3: exact kNN (top-32 smallest (d2, idx)) ----------
__global__ void __launch_bounds__(256) knn_kernel(const float* __restrict__ xyz,
                                                  const float* __restrict__ newxyz,
                                                  unsigned short* __restrict__ knn_out) {
    __shared__ unsigned long long wmin[2][4];
    int s = blockIdx.x, b = blockIdx.y, tid = threadIdx.x;
    const float* c3 = newxyz + ((size_t)b * NP + s) * 3;
    float cx = c3[0], cy = c3[1], cz = c3[2];
    float sn = sq3_exact(cx, cy, cz);
    const float* xb = xyz + (size_t)b * NN * 3;
    unsigned long long key[16], mymin = ~0ull;
#pragma unroll
    for (int j = 0; j < 16; j++) {
        int n = j * 256 + tid;
        float x = xb[n * 3 + 0], y = xb[n * 3 + 1], z = xb[n * 3 + 2];
        float sx = sq3_exact(x, y, z);
        float dt = dot3_exact(cx, cy, cz, x, y, z);
        float d2 = d2_exact(sn, sx, dt);
        unsigned long long kk = ((unsigned long long)f32_sortable(d2) << 32) | (unsigned)n;
        key[j] = kk;
        mymin = umin64(mymin, kk);
    }
    unsigned short* out = knn_out + ((size_t)b * NP + s) * KK;
    for (int r = 0; r < KK; r++) {
        unsigned long long m = mymin;
#pragma unroll
        for (int off = 32; off > 0; off >>= 1) {
            unsigned long long om = __shfl_xor(m, off);
            m = umin64(m, om);
        }
        int par = r & 1;
        if ((tid & 63) == 0) wmin[par][tid >> 6] = m;
        __syncthreads();
        m = umin64(umin64(wmin[par][0], wmin[par][1]),
                   umin64(wmin[par][2], wmin[par][3]));
        int n = (int)(uint32_t)m;
        if (tid == 0) out[r] = (unsigned short)n;
        if (tid == (n & 255)) {                         // owner invalidates + recomputes its min
            key[n >> 8] = ~0ull;
            unsigned long long mm = ~0ull;
#pragma unroll
            for (int j = 0; j < 16; j++) mm = umin64(mm, key[j]);
            mymin = mm;
        }
    }
}

// ---------- kernel 4: gather + 3-layer MLP + maxpool over k ----------
__global__ void __launch_bounds__(256) mlp_kernel(const float* __restrict__ xyz,
                                                  const __hip_bfloat16* __restrict__ ptsT,
                                                  const unsigned short* __restrict__ knn_idx,
                                                  const float* __restrict__ W1, const float* __restrict__ b1,
                                                  const float* __restrict__ W2, const float* __restrict__ b2,
                                                  const float* __restrict__ W3, const float* __restrict__ b3,
                                                  float* __restrict__ out_np) {
    __shared__ __attribute__((aligned(16))) float Wl[128 * 65];
    __shared__ __attribute__((aligned(16))) float gt [CIN * 36];
    __shared__ __attribute__((aligned(16))) float h1t[64 * 36];
    __shared__ __attribute__((aligned(16))) float h2t[64 * 36];
    __shared__ int   nidx[KK];
    __shared__ float pmax[256];
    int s = blockIdx.x, b = blockIdx.y, tid = threadIdx.x;

    if (tid < KK) nidx[tid] = (int)knn_idx[((size_t)b * NP + s) * KK + tid];
    for (int i = tid; i < 64 * 67; i += 256) Wl[i] = W1[i];
    __syncthreads();

    {
        int k = tid >> 3, l8 = tid & 7;
        int n = nidx[k];
        const float* xp = xyz + ((size_t)b * NN + n) * 3;
        const __hip_bfloat16* pp = ptsT + ((size_t)b * NN + n) * CP;
        for (int c = l8; c < CIN; c += 8) {
            float v = (c < 3) ? xp[c] : __bfloat162float(pp[c - 3]);
            gt[c * 36 + k] = v;
        }
    }
    __syncthreads();

    const int o  = tid & 63;
    const int kq = tid >> 6;
    { // ---- layer 1: 67 -> 64 ----
        float acc[8];
        float bias = b1[o];
#pragma unroll
        for (int i = 0; i < 8; i++) acc[i] = bias;
        for (int c = 0; c < CIN; c++) {
            float w = Wl[o * 67 + c];
            const float4* gp = (const float4*)&gt[c * 36 + (kq << 3)];
            float4 ga = gp[0], gb = gp[1];
            acc[0] = fmaf(w, ga.x, acc[0]); acc[1] = fmaf(w, ga.y, acc[1]);
            acc[2] = fmaf(w, ga.z, acc[2]); acc[3] = fmaf(w, ga.w, acc[3]);
            acc[4] = fmaf(w, gb.x, acc[4]); acc[5] = fmaf(w, gb.y, acc[5]);
            acc[6] = fmaf(w, gb.z, acc[6]); acc[7] = fmaf(w, gb.w, acc[7]);
        }
        float4 r0 = make_float4(fmaxf(acc[0], 0.f), fmaxf(acc[1], 0.f), fmaxf(acc[2], 0.f), fmaxf(acc[3], 0.f));
        float4 r1 = make_float4(fmaxf(acc[4], 0.f), fmaxf(acc[5], 0.f), fmaxf(acc[6], 0.f), fmaxf(acc[7], 0.f));
        *(float4*)&h1t[o * 36 + (kq << 3)]     = r0;
        *(float4*)&h1t[o * 36 + (kq << 3) + 4] = r1;
    }
    __syncthreads();
    for (int i = tid; i < 64 * 64; i += 256) Wl[(i >> 6) * 65 + (i & 63)] = W2[i];
    __syncthreads();
    { // ---- layer 2: 64 -> 64 ----
        float acc[8];
        float bias = b2[o];
#pragma unroll
        for (int i = 0; i < 8; i++) acc[i] = bias;
        for (int c = 0; c < 64; c++) {
            float w = Wl[o * 65 + c];
            const float4* gp = (const float4*)&h1t[c * 36 + (kq << 3)];
            float4 ga = gp[0], gb = gp[1];
            acc[0] = fmaf(w, ga.x, acc[0]); acc[1] = fmaf(w, ga.y, acc[1]);
            acc[2] = fmaf(w, ga.z, acc[2]); acc[3] = fmaf(w, ga.w, acc[3]);
            acc[4] = fmaf(w, gb.x, acc[4]); acc[5] = fmaf(w, gb.y, acc[5]);
            acc[6] = fmaf(w, gb.z, acc[6]); acc[7] = fmaf(w, gb.w, acc[7]);
        }
        float4 r0 = make_float4(fmaxf(acc[0], 0.f), fmaxf(acc[1], 0.f), fmaxf(acc[2], 0.f), fmaxf(acc[3], 0.f));
        float4 r1 = make_float4(fmaxf(acc[4], 0.f), fmaxf(acc[5], 0.f), fmaxf(acc[6], 0.f), fmaxf(acc[7], 0.f));
        *(float4*)&h2t[o * 36 + (kq << 3)]     = r0;
        *(float4*)&h2t[o * 36 + (kq << 3) + 4] = r1;
    }
    __syncthreads();
    for (int i = tid; i < 128 * 64; i += 256) Wl[(i >> 6) * 65 + (i & 63)] = W3[i];
    __syncthreads();
    { // ---- layer 3: 64 -> 128, fused maxpool ----
        const int o3 = tid & 127;
        const int kq3 = tid >> 7;
        float acc[16];
        float bias = b3[o3];
#pragma unroll
        for (int i = 0; i < 16; i++) acc[i] = bias;
        for (int c = 0; c < 64; c++) {
            float w = Wl[o3 * 65 + c];
            const float4* hp = (const float4*)&h2t[c * 36 + (kq3 << 4)];
            float4 h0 = hp[0], h1v = hp[1], h2v = hp[2], h3v = hp[3];
            acc[0]  = fmaf(w, h0.x,  acc[0]);  acc[1]  = fmaf(w, h0.y,  acc[1]);
            acc[2]  = fmaf(w, h0.z,  acc[2]);  acc[3]  = fmaf(w, h0.w,  acc[3]);
            acc[4]  = fmaf(w, h1v.x, acc[4]);  acc[5]  = fmaf(w, h1v.y, acc[5]);
            acc[6]  = fmaf(w, h1v.z, acc[6]);  acc[7]  = fmaf(w, h1v.w, acc[7]);
            acc[8]  = fmaf(w, h2v.x, acc[8]);  acc[9]  = fmaf(w, h2v.y, acc[9]);
            acc[10] = fmaf(w, h2v.z, acc[10]); acc[11] = fmaf(w, h2v.w, acc[11]);
            acc[12] = fmaf(w, h3v.x, acc[12]); acc[13] = fmaf(w, h3v.y, acc[13]);
            acc[14] = fmaf(w, h3v.z, acc[14]); acc[15] = fmaf(w, h3v.w, acc[15]);
        }
        float m = acc[0];
#pragma unroll
        for (int i = 1; i < 16; i++) m = fmaxf(m, acc[i]);
        m = fmaxf(m, 0.0f);
        pmax[tid] = m;
    }
    __syncthreads();
    if (tid < 128) {
        float m = fmaxf(pmax[tid], pmax[tid + 128]);
        out_np[((size_t)b * H3 + tid) * NP + s] = m;
    }
}

extern "C" void kernel_launch(void* const* d_in, const int* in_sizes, int n_in,
                              void* d_out, int out_size, void* d_ws, size_t ws_size,
                              hipStream_t stream) {
    (void)in_sizes; (void)n_in; (void)out_size; (void)ws_size;
    const float* xyz = (const float*)d_in[0];
    const float* pts = (const float*)d_in[1];
    const float* W1  = (const float*)d_in[2];
    const float* b1  = (const float*)d_in[3];
    const float* W2  = (const float*)d_in[4];
    const float* b2  = (const float*)d_in[5];
    const float* W3  = (const float*)d_in[6];
    const float* b3  = (const float*)d_in[7];

    float* out    = (float*)d_out;
    float* newxyz = out;                       // (B, NP, 3)
    float* newpts = out + (size_t)BB * NP * 3; // (B, 128, NP)

    __hip_bfloat16* ptsT = (__hip_bfloat16*)d_ws;
    unsigned short* knni = (unsigned short*)((char*)d_ws + (size_t)BB * NN * CP * sizeof(__hip_bfloat16));

    transpose_pts<<<dim3(NN / 64, BB), 256, 0, stream>>>(pts, ptsT);
    fps_kernel  <<<BB, FPS_T, 0, stream>>>(xyz, newxyz);
    knn_kernel  <<<dim3(NP, BB), 256, 0, stream>>>(xyz, newxyz, knni);
    mlp_kernel  <<<dim3(NP, BB), 256, 0, stream>>>(xyz, ptsT, knni, W1, b1, W2, b2, W3, b3, newpts);
}

// Round 3
// 1409.111 us; speedup vs baseline: 1.3760x; 1.2222x over previous
//
#include <hip/hip_runtime.h>
#include <hip/hip_bf16.h>
#include <stdint.h>

// Problem constants (fixed by setup_inputs).
#define BB   16
#define NN   4096
#define NP   1024
#define KK   32
#define CP   64
#define CIN  67    // 3 + 64
#define H3   128

// ---------- exact-rounding helpers (match numpy op-by-op; no fma contraction) ----------
__device__ __forceinline__ float sq3_exact(float x, float y, float z) {
#pragma clang fp contract(off)
    float a = x * x;
    float b = y * y;
    float c = z * z;
    return (a + b) + c;
}
__device__ __forceinline__ float dot3_exact(float ax, float ay, float az,
                                            float bx, float by, float bz) {
#pragma clang fp contract(off)
    float a = ax * bx;
    float b = ay * by;
    float c = az * bz;
    return (a + b) + c;
}
__device__ __forceinline__ float d2_exact(float sn, float sx, float dt) {
#pragma clang fp contract(off)
    return (sn + sx) - 2.0f * dt;
}
__device__ __forceinline__ uint32_t f32_sortable(float f) {
    uint32_t u = __float_as_uint(f);
    return (u & 0x80000000u) ? ~u : (u | 0x80000000u);
}
__device__ __forceinline__ unsigned long long umax64(unsigned long long a, unsigned long long b) {
    return a > b ? a : b;
}

// ---------- DPP wave64 u64-max reduce (VALU pipe; avoids ds_bpermute chains) ----------
// bound_ctrl=true -> invalid lanes read 0, which is the identity for our
// nonnegative keys. After row_shr 1/2/4/8 + row_bcast:15 + row_bcast:31,
// lane 63 holds the full-wave max; readlane broadcasts it to all lanes (SGPR).
template <int CTRL>
__device__ __forceinline__ unsigned long long dpp_umax_step(unsigned long long k) {
    uint32_t lo = (uint32_t)k, hi = (uint32_t)(k >> 32);
    uint32_t olo = (uint32_t)__builtin_amdgcn_update_dpp(0, (int)lo, CTRL, 0xf, 0xf, true);
    uint32_t ohi = (uint32_t)__builtin_amdgcn_update_dpp(0, (int)hi, CTRL, 0xf, 0xf, true);
    unsigned long long ok = ((unsigned long long)ohi << 32) | olo;
    return k > ok ? k : ok;
}
__device__ __forceinline__ unsigned long long wave_umax64_dpp(unsigned long long k) {
    k = dpp_umax_step<0x111>(k);   // row_shr:1
    k = dpp_umax_step<0x112>(k);   // row_shr:2
    k = dpp_umax_step<0x114>(k);   // row_shr:4
    k = dpp_umax_step<0x118>(k);   // row_shr:8
    k = dpp_umax_step<0x142>(k);   // row_bcast:15
    k = dpp_umax_step<0x143>(k);   // row_bcast:31
    uint32_t lo = (uint32_t)__builtin_amdgcn_readlane((int)(uint32_t)k, 63);
    uint32_t hi = (uint32_t)__builtin_amdgcn_readlane((int)(uint32_t)(k >> 32), 63);
    return ((unsigned long long)hi << 32) | lo;
}

// ---------- kernel 1: transpose points (B,Cp,N) -> bf16 (B,N,Cp) ----------
__global__ void __launch_bounds__(256) transpose_pts(const float* __restrict__ pts,
                                                     __hip_bfloat16* __restrict__ ptsT) {
    __shared__ float tile[64][65];
    int b  = blockIdx.y;
    int n0 = blockIdx.x * 64;
    int tx = threadIdx.x & 63, ty = threadIdx.x >> 6;   // 64 x 4
    const float* src = pts + (size_t)b * CP * NN;
    for (int c = ty; c < 64; c += 4)
        tile[c][tx] = src[c * NN + n0 + tx];
    __syncthreads();
    __hip_bfloat16* dst = ptsT + ((size_t)b * NN + n0) * CP;
    for (int nn2 = ty; nn2 < 64; nn2 += 4)
        dst[nn2 * CP + tx] = __float2bfloat16(tile[tx][nn2]);
}

// ---------- kernel 2: FPS, one block per batch ----------
// 256 threads (1 wave/SIMD), 16 pts/thread pinned in VGPRs. Per-iteration
// critical chain: ds_read_b128 centroid (broadcast) -> 16-pt dist update
// (VALU) -> DPP wave u64-max (VALU, ~70cyc; R1's ds_bpermute chain was ~780)
// -> 1 LDS write + barrier + 4-key combine.
// Key = (bits(bv)<<32) | (4095-idx): bv>=0 so raw bits are order-isomorphic;
// umax == (max d, tie -> min idx), matching jnp.argmax.
#define FPS_T 256
#define FPS_J (NN / FPS_T)   // 16

__global__ void __launch_bounds__(FPS_T, 1) fps_kernel(const float* __restrict__ xyz,
                                                       float* __restrict__ newxyz) {
    __shared__ __attribute__((aligned(16))) float4 sxyz[NN];   // 64 KB
    __shared__ int farr[NP];
    __shared__ __attribute__((aligned(16))) unsigned long long kbuf[2][4];
    int b = blockIdx.x;
    int tid = threadIdx.x;
    const float* xb = xyz + (size_t)b * NN * 3;
    float px[FPS_J], py[FPS_J], pz[FPS_J], dmin[FPS_J];
#pragma unroll
    for (int j = 0; j < FPS_J; j++) {
        int n = j * FPS_T + tid;
        float x = xb[n * 3 + 0], y = xb[n * 3 + 1], z = xb[n * 3 + 2];
        px[j] = x; py[j] = y; pz[j] = z;
        sxyz[n] = make_float4(x, y, z, 0.0f);
        dmin[j] = 1e10f;                              // matches 10000000000.0 init
    }
#pragma unroll
    for (int j = 0; j < FPS_J; j++) {                 // pin to VGPRs: no LDS remat
        asm volatile("" : "+v"(px[j]), "+v"(py[j]), "+v"(pz[j]));
    }
    if (tid == 0) farr[0] = 0;                        // cents[0] = 0
    __syncthreads();
    int far = 0;
    for (int t = 0; t < NP - 1; t++) {
        float4 c = sxyz[far];                         // broadcast ds_read_b128
        float bv = -1.0f; int bj = 0;
#pragma unroll
        for (int j = 0; j < FPS_J; j++) {
            float dx = px[j] - c.x, dy = py[j] - c.y, dz = pz[j] - c.z;
            float s = sq3_exact(dx, dy, dz);
            float d = fminf(dmin[j], s);
            dmin[j] = d;
            bj = (d > bv) ? j : bj;                   // strict > : smaller idx wins ties
            bv = fmaxf(bv, d);
        }
        int bi = (bj << 8) | tid;                     // n = j*256 + tid
        unsigned long long key =
            ((unsigned long long)__float_as_uint(bv) << 32) | (unsigned)(NN - 1 - bi);
        key = wave_umax64_dpp(key);
        int par = t & 1;
        if ((tid & 63) == 0) kbuf[par][tid >> 6] = key;
        __syncthreads();
        const ulonglong2* kp = (const ulonglong2*)kbuf[par];
        ulonglong2 k0 = kp[0], k1 = kp[1];
        unsigned long long m = umax64(umax64(k0.x, k0.y), umax64(k1.x, k1.y));
        far = NN - 1 - (int)(unsigned)(m & 0xFFFFFFFFull);
        if (tid == 0) farr[t + 1] = far;
    }
    __syncthreads();
    float* nxb = newxyz + (size_t)b * NP * 3;
    for (int t = tid; t < NP; t += FPS_T) {
        float4 p = sxyz[farr[t]];
        nxb[t * 3 + 0] = p.x;
        nxb[t * 3 + 1] = p.y;
        nxb[t * 3 + 2] = p.z;
    }
}

// ---------- kernel 3: exact kNN (top-32 smallest (d2, idx)) ----------
// Keys complemented (ck = ~((sortable(d2)<<32)|n)) so the extraction min
// becomes a max with identity 0 -> DPP-reducible. 32 rounds of block max.
__global__ void __launch_bounds__(256) knn_kernel(const float* __restrict__ xyz,
                                                  const float* __restrict__ newxyz,
                                                  unsigned short* __restrict__ knn_out) {
    __shared__ __attribute__((aligned(16))) unsigned long long kb[2][4];
    int s = blockIdx.x, b = blockIdx.y, tid = threadIdx.x;
    const float* c3 = newxyz + ((size_t)b * NP + s) * 3;
    float cx = c3[0], cy = c3[1], cz = c3[2];
    float sn = sq3_exact(cx, cy, cz);
    const float* xb = xyz + (size_t)b * NN * 3;
    unsigned long long ck[16], mymax = 0;
#pragma unroll
    for (int j = 0; j < 16; j++) {
        int n = j * 256 + tid;
        float x = xb[n * 3 + 0], y = xb[n * 3 + 1], z = xb[n * 3 + 2];
        float sx = sq3_exact(x, y, z);
        float dt = dot3_exact(cx, cy, cz, x, y, z);
        float d2 = d2_exact(sn, sx, dt);
        unsigned long long c = ~(((unsigned long long)f32_sortable(d2) << 32) | (unsigned)n);
        ck[j] = c;
        mymax = umax64(mymax, c);
    }
    unsigned short* out = knn_out + ((size_t)b * NP + s) * KK;
    for (int r = 0; r < KK; r++) {
        unsigned long long m = wave_umax64_dpp(mymax);
        int par = r & 1;
        if ((tid & 63) == 0) kb[par][tid >> 6] = m;
        __syncthreads();
        const ulonglong2* kp = (const ulonglong2*)kb[par];
        ulonglong2 k0 = kp[0], k1 = kp[1];
        m = umax64(umax64(k0.x, k0.y), umax64(k1.x, k1.y));
        int n = (int)(uint32_t)(~(uint32_t)m);          // low 32 bits of ~m = n
        if (tid == 0) out[r] = (unsigned short)n;
        if (tid == (n & 255)) {                         // owner invalidates + recomputes
            ck[n >> 8] = 0;
            unsigned long long mm = 0;
#pragma unroll
            for (int j = 0; j < 16; j++) mm = umax64(mm, ck[j]);
            mymax = mm;
        }
    }
}

// ---------- kernel 4: gather + 3-layer MLP + maxpool over k ----------
__global__ void __launch_bounds__(256) mlp_kernel(const float* __restrict__ xyz,
                                                  const __hip_bfloat16* __restrict__ ptsT,
                                                  const unsigned short* __restrict__ knn_idx,
                                                  const float* __restrict__ W1, const float* __restrict__ b1,
                                                  const float* __restrict__ W2, const float* __restrict__ b2,
                                                  const float* __restrict__ W3, const float* __restrict__ b3,
                                                  float* __restrict__ out_np) {
    __shared__ __attribute__((aligned(16))) float Wl[128 * 65];
    __shared__ __attribute__((aligned(16))) float gt [CIN * 36];
    __shared__ __attribute__((aligned(16))) float h1t[64 * 36];
    __shared__ __attribute__((aligned(16))) float h2t[64 * 36];
    __shared__ int   nidx[KK];
    __shared__ float pmax[256];
    int s = blockIdx.x, b = blockIdx.y, tid = threadIdx.x;

    if (tid < KK) nidx[tid] = (int)knn_idx[((size_t)b * NP + s) * KK + tid];
    for (int i = tid; i < 64 * 67; i += 256) Wl[i] = W1[i];
    __syncthreads();

    {
        int k = tid >> 3, l8 = tid & 7;
        int n = nidx[k];
        const float* xp = xyz + ((size_t)b * NN + n) * 3;
        const __hip_bfloat16* pp = ptsT + ((size_t)b * NN + n) * CP;
        for (int c = l8; c < CIN; c += 8) {
            float v = (c < 3) ? xp[c] : __bfloat162float(pp[c - 3]);
            gt[c * 36 + k] = v;
        }
    }
    __syncthreads();

    const int o  = tid & 63;
    const int kq = tid >> 6;
    { // ---- layer 1: 67 -> 64 ----
        float acc[8];
        float bias = b1[o];
#pragma unroll
        for (int i = 0; i < 8; i++) acc[i] = bias;
        for (int c = 0; c < CIN; c++) {
            float w = Wl[o * 67 + c];
            const float4* gp = (const float4*)&gt[c * 36 + (kq << 3)];
            float4 ga = gp[0], gb = gp[1];
            acc[0] = fmaf(w, ga.x, acc[0]); acc[1] = fmaf(w, ga.y, acc[1]);
            acc[2] = fmaf(w, ga.z, acc[2]); acc[3] = fmaf(w, ga.w, acc[3]);
            acc[4] = fmaf(w, gb.x, acc[4]); acc[5] = fmaf(w, gb.y, acc[5]);
            acc[6] = fmaf(w, gb.z, acc[6]); acc[7] = fmaf(w, gb.w, acc[7]);
        }
        float4 r0 = make_float4(fmaxf(acc[0], 0.f), fmaxf(acc[1], 0.f), fmaxf(acc[2], 0.f), fmaxf(acc[3], 0.f));
        float4 r1 = make_float4(fmaxf(acc[4], 0.f), fmaxf(acc[5], 0.f), fmaxf(acc[6], 0.f), fmaxf(acc[7], 0.f));
        *(float4*)&h1t[o * 36 + (kq << 3)]     = r0;
        *(float4*)&h1t[o * 36 + (kq << 3) + 4] = r1;
    }
    __syncthreads();
    for (int i = tid; i < 64 * 64; i += 256) Wl[(i >> 6) * 65 + (i & 63)] = W2[i];
    __syncthreads();
    { // ---- layer 2: 64 -> 64 ----
        float acc[8];
        float bias = b2[o];
#pragma unroll
        for (int i = 0; i < 8; i++) acc[i] = bias;
        for (int c = 0; c < 64; c++) {
            float w = Wl[o * 65 + c];
            const float4* gp = (const float4*)&h1t[c * 36 + (kq << 3)];
            float4 ga = gp[0], gb = gp[1];
            acc[0] = fmaf(w, ga.x, acc[0]); acc[1] = fmaf(w, ga.y, acc[1]);
            acc[2] = fmaf(w, ga.z, acc[2]); acc[3] = fmaf(w, ga.w, acc[3]);
            acc[4] = fmaf(w, gb.x, acc[4]); acc[5] = fmaf(w, gb.y, acc[5]);
            acc[6] = fmaf(w, gb.z, acc[6]); acc[7] = fmaf(w, gb.w, acc[7]);
        }
        float4 r0 = make_float4(fmaxf(acc[0], 0.f), fmaxf(acc[1], 0.f), fmaxf(acc[2], 0.f), fmaxf(acc[3], 0.f));
        float4 r1 = make_float4(fmaxf(acc[4], 0.f), fmaxf(acc[5], 0.f), fmaxf(acc[6], 0.f), fmaxf(acc[7], 0.f));
        *(float4*)&h2t[o * 36 + (kq << 3)]     = r0;
        *(float4*)&h2t[o * 36 + (kq << 3) + 4] = r1;
    }
    __syncthreads();
    for (int i = tid; i < 128 * 64; i += 256) Wl[(i >> 6) * 65 + (i & 63)] = W3[i];
    __syncthreads();
    { // ---- layer 3: 64 -> 128, fused maxpool ----
        const int o3 = tid & 127;
        const int kq3 = tid >> 7;
        float acc[16];
        float bias = b3[o3];
#pragma unroll
        for (int i = 0; i < 16; i++) acc[i] = bias;
        for (int c = 0; c < 64; c++) {
            float w = Wl[o3 * 65 + c];
            const float4* hp = (const float4*)&h2t[c * 36 + (kq3 << 4)];
            float4 h0 = hp[0], h1v = hp[1], h2v = hp[2], h3v = hp[3];
            acc[0]  = fmaf(w, h0.x,  acc[0]);  acc[1]  = fmaf(w, h0.y,  acc[1]);
            acc[2]  = fmaf(w, h0.z,  acc[2]);  acc[3]  = fmaf(w, h0.w,  acc[3]);
            acc[4]  = fmaf(w, h1v.x, acc[4]);  acc[5]  = fmaf(w, h1v.y, acc[5]);
            acc[6]  = fmaf(w, h1v.z, acc[6]);  acc[7]  = fmaf(w, h1v.w, acc[7]);
            acc[8]  = fmaf(w, h2v.x, acc[8]);  acc[9]  = fmaf(w, h2v.y, acc[9]);
            acc[10] = fmaf(w, h2v.z, acc[10]); acc[11] = fmaf(w, h2v.w, acc[11]);
            acc[12] = fmaf(w, h3v.x, acc[12]); acc[13] = fmaf(w, h3v.y, acc[13]);
            acc[14] = fmaf(w, h3v.z, acc[14]); acc[15] = fmaf(w, h3v.w, acc[15]);
        }
        float m = acc[0];
#pragma unroll
        for (int i = 1; i < 16; i++) m = fmaxf(m, acc[i]);
        m = fmaxf(m, 0.0f);
        pmax[tid] = m;
    }
    __syncthreads();
    if (tid < 128) {
        float m = fmaxf(pmax[tid], pmax[tid + 128]);
        out_np[((size_t)b * H3 + tid) * NP + s] = m;
    }
}

extern "C" void kernel_launch(void* const* d_in, const int* in_sizes, int n_in,
                              void* d_out, int out_size, void* d_ws, size_t ws_size,
                              hipStream_t stream) {
    (void)in_sizes; (void)n_in; (void)out_size; (void)ws_size;
    const float* xyz = (const float*)d_in[0];
    const float* pts = (const float*)d_in[1];
    const float* W1  = (const float*)d_in[2];
    const float* b1  = (const float*)d_in[3];
    const float* W2  = (const float*)d_in[4];
    const float* b2  = (const float*)d_in[5];
    const float* W3  = (const float*)d_in[6];
    const float* b3  = (const float*)d_in[7];

    float* out    = (float*)d_out;
    float* newxyz = out;                       // (B, NP, 3)
    float* newpts = out + (size_t)BB * NP * 3; // (B, 128, NP)

    __hip_bfloat16* ptsT = (__hip_bfloat16*)d_ws;
    unsigned short* knni = (unsigned short*)((char*)d_ws + (size_t)BB * NN * CP * sizeof(__hip_bfloat16));

    transpose_pts<<<dim3(NN / 64, BB), 256, 0, stream>>>(pts, ptsT);
    fps_kernel  <<<BB, FPS_T, 0, stream>>>(xyz, newxyz);
    knn_kernel  <<<dim3(NP, BB), 256, 0, stream>>>(xyz, newxyz, knni);
    mlp_kernel  <<<dim3(NP, BB), 256, 0, stream>>>(xyz, ptsT, knni, W1, b1, W2, b2, W3, b3, newpts);
}

// Round 4
// 1060.012 us; speedup vs baseline: 1.8291x; 1.3293x over previous
//
#include <hip/hip_runtime.h>
#include <hip/hip_bf16.h>
#include <stdint.h>
#include <string.h>

// Problem constants (fixed by setup_inputs).
#define BB   16
#define NN   4096
#define NP   1024
#define KK   32
#define CP   64
#define CIN  67    // 3 + 64
#define H3   128

typedef __attribute__((ext_vector_type(8))) short short8;
typedef __attribute__((ext_vector_type(4))) float floatx4;

// ---------- exact-rounding helpers (match numpy op-by-op; no fma contraction) ----------
__device__ __forceinline__ float sq3_exact(float x, float y, float z) {
#pragma clang fp contract(off)
    float a = x * x;
    float b = y * y;
    float c = z * z;
    return (a + b) + c;
}
__device__ __forceinline__ float dot3_exact(float ax, float ay, float az,
                                            float bx, float by, float bz) {
#pragma clang fp contract(off)
    float a = ax * bx;
    float b = ay * by;
    float c = az * bz;
    return (a + b) + c;
}
__device__ __forceinline__ float d2_exact(float sn, float sx, float dt) {
#pragma clang fp contract(off)
    return (sn + sx) - 2.0f * dt;
}
__device__ __forceinline__ uint32_t f32_sortable(float f) {
    uint32_t u = __float_as_uint(f);
    return (u & 0x80000000u) ? ~u : (u | 0x80000000u);
}
__device__ __forceinline__ unsigned long long umax64(unsigned long long a, unsigned long long b) {
    return a > b ? a : b;
}
__device__ __forceinline__ unsigned short bf16_bits(float f) {
    __hip_bfloat16 h = __float2bfloat16(f);
    unsigned short us;
    __builtin_memcpy(&us, &h, 2);
    return us;
}

// ---------- DPP wave64 u64-max reduce (VALU pipe) ----------
template <int CTRL>
__device__ __forceinline__ unsigned long long dpp_umax_step(unsigned long long k) {
    uint32_t lo = (uint32_t)k, hi = (uint32_t)(k >> 32);
    uint32_t olo = (uint32_t)__builtin_amdgcn_update_dpp(0, (int)lo, CTRL, 0xf, 0xf, true);
    uint32_t ohi = (uint32_t)__builtin_amdgcn_update_dpp(0, (int)hi, CTRL, 0xf, 0xf, true);
    unsigned long long ok = ((unsigned long long)ohi << 32) | olo;
    return k > ok ? k : ok;
}
__device__ __forceinline__ unsigned long long wave_umax64_dpp(unsigned long long k) {
    k = dpp_umax_step<0x111>(k);   // row_shr:1
    k = dpp_umax_step<0x112>(k);   // row_shr:2
    k = dpp_umax_step<0x114>(k);   // row_shr:4
    k = dpp_umax_step<0x118>(k);   // row_shr:8
    k = dpp_umax_step<0x142>(k);   // row_bcast:15
    k = dpp_umax_step<0x143>(k);   // row_bcast:31
    uint32_t lo = (uint32_t)__builtin_amdgcn_readlane((int)(uint32_t)k, 63);
    uint32_t hi = (uint32_t)__builtin_amdgcn_readlane((int)(uint32_t)(k >> 32), 63);
    return ((unsigned long long)hi << 32) | lo;
}

// ---------- kernel 1: transpose points (B,Cp,N) -> bf16 (B,N,Cp) ----------
__global__ void __launch_bounds__(256) transpose_pts(const float* __restrict__ pts,
                                                     __hip_bfloat16* __restrict__ ptsT) {
    __shared__ float tile[64][65];
    int b  = blockIdx.y;
    int n0 = blockIdx.x * 64;
    int tx = threadIdx.x & 63, ty = threadIdx.x >> 6;   // 64 x 4
    const float* src = pts + (size_t)b * CP * NN;
    for (int c = ty; c < 64; c += 4)
        tile[c][tx] = src[c * NN + n0 + tx];
    __syncthreads();
    __hip_bfloat16* dst = ptsT + ((size_t)b * NN + n0) * CP;
    for (int nn2 = ty; nn2 < 64; nn2 += 4)
        dst[nn2 * CP + tx] = __float2bfloat16(tile[tx][nn2]);
}

// ---------- kernel 1b: weights -> bf16, channel-reordered+padded ----------
// w1p: [64][96]  c'=0..63 <- W1[o][3+c'] (points), 64..66 <- W1[o][c'-64] (xyz), 67..95 <- 0
// w2p: [64][64], w3p: [128][64] row-major bf16.
__global__ void __launch_bounds__(256) prep_weights(const float* __restrict__ W1,
                                                    const float* __restrict__ W2,
                                                    const float* __restrict__ W3,
                                                    short* __restrict__ w1p,
                                                    short* __restrict__ w2p,
                                                    short* __restrict__ w3p) {
    int tid = blockIdx.x * 256 + threadIdx.x;
    int tot = gridDim.x * 256;
    for (int i = tid; i < 64 * 96; i += tot) {
        int o = i / 96, c = i % 96;
        float v = (c < 64) ? W1[o * CIN + 3 + c] : ((c < 67) ? W1[o * CIN + (c - 64)] : 0.0f);
        w1p[i] = (short)bf16_bits(v);
    }
    for (int i = tid; i < 64 * 64; i += tot)  w2p[i] = (short)bf16_bits(W2[i]);
    for (int i = tid; i < 128 * 64; i += tot) w3p[i] = (short)bf16_bits(W3[i]);
}

// ---------- kernel 2: FPS, one block per batch ----------
// 512 threads, 8 pts/thread pinned in VGPRs (halves the dominant update-loop
// issue vs 256 thr; reduce is DPP so extra waves are cheap — R1's 512-thr
// regression was the ds_bpermute chain, not the wave count).
#define FPS_T 512
#define FPS_J (NN / FPS_T)   // 8

__global__ void __launch_bounds__(FPS_T, 1) fps_kernel(const float* __restrict__ xyz,
                                                       float* __restrict__ newxyz) {
    __shared__ __attribute__((aligned(16))) float4 sxyz[NN];   // 64 KB
    __shared__ int farr[NP];
    __shared__ __attribute__((aligned(16))) unsigned long long kbuf[2][8];
    int b = blockIdx.x;
    int tid = threadIdx.x;
    const float* xb = xyz + (size_t)b * NN * 3;
    float px[FPS_J], py[FPS_J], pz[FPS_J], dmin[FPS_J];
#pragma unroll
    for (int j = 0; j < FPS_J; j++) {
        int n = j * FPS_T + tid;
        float x = xb[n * 3 + 0], y = xb[n * 3 + 1], z = xb[n * 3 + 2];
        px[j] = x; py[j] = y; pz[j] = z;
        sxyz[n] = make_float4(x, y, z, 0.0f);
        dmin[j] = 1e10f;                              // matches 10000000000.0 init
    }
#pragma unroll
    for (int j = 0; j < FPS_J; j++) {                 // pin to VGPRs: no LDS remat
        asm volatile("" : "+v"(px[j]), "+v"(py[j]), "+v"(pz[j]));
    }
    if (tid == 0) farr[0] = 0;                        // cents[0] = 0
    __syncthreads();
    int far = 0;
    for (int t = 0; t < NP - 1; t++) {
        float4 c = sxyz[far];                         // broadcast ds_read_b128
        float bv = -1.0f; int bj = 0;
#pragma unroll
        for (int j = 0; j < FPS_J; j++) {
            float dx = px[j] - c.x, dy = py[j] - c.y, dz = pz[j] - c.z;
            float s = sq3_exact(dx, dy, dz);
            float d = fminf(dmin[j], s);
            dmin[j] = d;
            bj = (d > bv) ? j : bj;                   // strict > : smaller idx wins ties
            bv = fmaxf(bv, d);
        }
        int bi = bj * FPS_T + tid;
        unsigned long long key =
            ((unsigned long long)__float_as_uint(bv) << 32) | (unsigned)(NN - 1 - bi);
        key = wave_umax64_dpp(key);
        int par = t & 1;
        if ((tid & 63) == 0) kbuf[par][tid >> 6] = key;
        __syncthreads();
        const ulonglong2* kp = (const ulonglong2*)kbuf[par];
        ulonglong2 k0 = kp[0], k1 = kp[1], k2 = kp[2], k3 = kp[3];
        unsigned long long m = umax64(umax64(umax64(k0.x, k0.y), umax64(k1.x, k1.y)),
                                      umax64(umax64(k2.x, k2.y), umax64(k3.x, k3.y)));
        far = NN - 1 - (int)(unsigned)(m & 0xFFFFFFFFull);
        if (tid == 0) farr[t + 1] = far;
    }
    __syncthreads();
    float* nxb = newxyz + (size_t)b * NP * 3;
    for (int t = tid; t < NP; t += FPS_T) {
        float4 p = sxyz[farr[t]];
        nxb[t * 3 + 0] = p.x;
        nxb[t * 3 + 1] = p.y;
        nxb[t * 3 + 2] = p.z;
    }
}

// ---------- kernel 3: exact kNN (top-32 smallest (d2, idx)) ----------
__global__ void __launch_bounds__(256) knn_kernel(const float* __restrict__ xyz,
                                                  const float* __restrict__ newxyz,
                                                  unsigned short* __restrict__ knn_out) {
    __shared__ __attribute__((aligned(16))) unsigned long long kb[2][4];
    int s = blockIdx.x, b = blockIdx.y, tid = threadIdx.x;
    const float* c3 = newxyz + ((size_t)b * NP + s) * 3;
    float cx = c3[0], cy = c3[1], cz = c3[2];
    float sn = sq3_exact(cx, cy, cz);
    const float* xb = xyz + (size_t)b * NN * 3;
    unsigned long long ck[16], mymax = 0;
#pragma unroll
    for (int j = 0; j < 16; j++) {
        int n = j * 256 + tid;
        float x = xb[n * 3 + 0], y = xb[n * 3 + 1], z = xb[n * 3 + 2];
        float sx = sq3_exact(x, y, z);
        float dt = dot3_exact(cx, cy, cz, x, y, z);
        float d2 = d2_exact(sn, sx, dt);
        unsigned long long c = ~(((unsigned long long)f32_sortable(d2) << 32) | (unsigned)n);
        ck[j] = c;
        mymax = umax64(mymax, c);
    }
    unsigned short* out = knn_out + ((size_t)b * NP + s) * KK;
    for (int r = 0; r < KK; r++) {
        unsigned long long m = wave_umax64_dpp(mymax);
        int par = r & 1;
        if ((tid & 63) == 0) kb[par][tid >> 6] = m;
        __syncthreads();
        const ulonglong2* kp = (const ulonglong2*)kb[par];
        ulonglong2 k0 = kp[0], k1 = kp[1];
        m = umax64(umax64(k0.x, k0.y), umax64(k1.x, k1.y));
        int n = (int)(uint32_t)(~(uint32_t)m);          // low 32 bits of ~m = n
        if (tid == 0) out[r] = (unsigned short)n;
        if (tid == (n & 255)) {                         // owner invalidates + recomputes
            ck[n >> 8] = 0;
            unsigned long long mm = 0;
#pragma unroll
            for (int j = 0; j < 16; j++) mm = umax64(mm, ck[j]);
            mymax = mm;
        }
    }
}

// ---------- kernel 4: gather + 3-layer MLP via bf16 MFMA + maxpool ----------
// One (b,s) task per WAVE; 4 waves/block, wave-private LDS (no barriers).
// A-frags (G, h1, h2) from LDS rows (strides 96/72 bf16: 16B-aligned, bank-
// balanced for ds_read_b128). B-frags (weights) loaded directly from global
// bf16 (L2-resident; no LDS staging).
// MFMA 16x16x32 bf16: A[m=lane&15][k=quad*8+j], B[k=quad*8+j][n=lane&15]
// from row-major [n][k]; D: row m=quad*4+reg, col n=lane&15 [m89/m91].
__global__ void __launch_bounds__(256) mlp_mfma(const float* __restrict__ xyz,
                                                const __hip_bfloat16* __restrict__ ptsT,
                                                const unsigned short* __restrict__ knni,
                                                const short* __restrict__ w1p,
                                                const short* __restrict__ w2p,
                                                const short* __restrict__ w3p,
                                                const float* __restrict__ b1,
                                                const float* __restrict__ b2,
                                                const float* __restrict__ b3,
                                                float* __restrict__ out_np) {
    __shared__ __attribute__((aligned(16))) short lds[4 * 7680];   // 60 KB
    int tid  = threadIdx.x;
    int wave = tid >> 6, lane = tid & 63;
    int l15  = lane & 15, quad = lane >> 4;
    int gid  = blockIdx.x * 4 + wave;            // task = (b,s)
    int b    = gid >> 10, s = gid & (NP - 1);
    short* Gw  = lds + wave * 7680;              // 32 rows x 96 (c: 0..63 pts, 64..66 xyz, 67..95 zero)
    short* h1w = Gw + 32 * 96;                   // 32 rows x 72
    short* h2w = h1w + 32 * 72;                  // 32 rows x 72

    // bias preload (uniform per lane column)
    float b1v[4], b2v[4], b3v[8];
#pragma unroll
    for (int i = 0; i < 4; i++) b1v[i] = b1[l15 + 16 * i];
#pragma unroll
    for (int i = 0; i < 4; i++) b2v[i] = b2[l15 + 16 * i];
#pragma unroll
    for (int i = 0; i < 8; i++) b3v[i] = b3[l15 + 16 * i];

    // ---- gather: 32 neighbors -> G rows (2 lanes per row) ----
    {
        int r = lane & 31, h = lane >> 5;        // row, half
        int n = (int)knni[(size_t)gid * KK + r];
        const short8* prow = (const short8*)(ptsT + ((size_t)b * NN + n) * CP);
        short8 c0 = prow[h * 4 + 0], c1 = prow[h * 4 + 1];
        short8 c2 = prow[h * 4 + 2], c3 = prow[h * 4 + 3];
        short8* gdst = (short8*)&Gw[r * 96];
        gdst[h * 4 + 0] = c0; gdst[h * 4 + 1] = c1;
        gdst[h * 4 + 2] = c2; gdst[h * 4 + 3] = c3;
        short8 z8 = {0, 0, 0, 0, 0, 0, 0, 0};
        if (h == 0) {                            // cols 64..79 = [x,y,z,0...]
            const float* xp = xyz + ((size_t)b * NN + n) * 3;
            short8 v = z8;
            v[0] = (short)bf16_bits(xp[0]);
            v[1] = (short)bf16_bits(xp[1]);
            v[2] = (short)bf16_bits(xp[2]);
            gdst[8] = v; gdst[9] = z8;
        } else {                                 // cols 80..95 = 0
            gdst[10] = z8; gdst[11] = z8;
        }
    }

    // ---- layer 1: G(32x96) x W1p^T -> h1(32x64) ----
    {
        floatx4 acc[2][4];
#pragma unroll
        for (int mt = 0; mt < 2; mt++)
#pragma unroll
            for (int nt = 0; nt < 4; nt++) acc[mt][nt] = (floatx4)0.0f;
#pragma unroll
        for (int kt = 0; kt < 3; kt++) {
            short8 a0 = *(const short8*)&Gw[(l15) * 96 + kt * 32 + quad * 8];
            short8 a1 = *(const short8*)&Gw[(l15 + 16) * 96 + kt * 32 + quad * 8];
#pragma unroll
            for (int nt = 0; nt < 4; nt++) {
                short8 bf = *(const short8*)&w1p[(l15 + 16 * nt) * 96 + kt * 32 + quad * 8];
                acc[0][nt] = __builtin_amdgcn_mfma_f32_16x16x32_bf16(a0, bf, acc[0][nt], 0, 0, 0);
                acc[1][nt] = __builtin_amdgcn_mfma_f32_16x16x32_bf16(a1, bf, acc[1][nt], 0, 0, 0);
            }
        }
#pragma unroll
        for (int mt = 0; mt < 2; mt++)
#pragma unroll
            for (int nt = 0; nt < 4; nt++)
#pragma unroll
                for (int r = 0; r < 4; r++) {
                    float v = fmaxf(acc[mt][nt][r] + b1v[nt], 0.0f);
                    h1w[(quad * 4 + r + 16 * mt) * 72 + l15 + 16 * nt] = (short)bf16_bits(v);
                }
    }

    // ---- layer 2: h1(32x64) x W2^T -> h2(32x64) ----
    {
        floatx4 acc[2][4];
#pragma unroll
        for (int mt = 0; mt < 2; mt++)
#pragma unroll
            for (int nt = 0; nt < 4; nt++) acc[mt][nt] = (floatx4)0.0f;
#pragma unroll
        for (int kt = 0; kt < 2; kt++) {
            short8 a0 = *(const short8*)&h1w[(l15) * 72 + kt * 32 + quad * 8];
            short8 a1 = *(const short8*)&h1w[(l15 + 16) * 72 + kt * 32 + quad * 8];
#pragma unroll
            for (int nt = 0; nt < 4; nt++) {
                short8 bf = *(const short8*)&w2p[(l15 + 16 * nt) * 64 + kt * 32 + quad * 8];
                acc[0][nt] = __builtin_amdgcn_mfma_f32_16x16x32_bf16(a0, bf, acc[0][nt], 0, 0, 0);
                acc[1][nt] = __builtin_amdgcn_mfma_f32_16x16x32_bf16(a1, bf, acc[1][nt], 0, 0, 0);
            }
        }
#pragma unroll
        for (int mt = 0; mt < 2; mt++)
#pragma unroll
            for (int nt = 0; nt < 4; nt++)
#pragma unroll
                for (int r = 0; r < 4; r++) {
                    float v = fmaxf(acc[mt][nt][r] + b2v[nt], 0.0f);
                    h2w[(quad * 4 + r + 16 * mt) * 72 + l15 + 16 * nt] = (short)bf16_bits(v);
                }
    }

    // ---- layer 3: h2(32x64) x W3^T -> (32x128), fused maxpool over 32 pts ----
    {
        floatx4 acc[2][8];
#pragma unroll
        for (int mt = 0; mt < 2; mt++)
#pragma unroll
            for (int nt = 0; nt < 8; nt++) acc[mt][nt] = (floatx4)0.0f;
#pragma unroll
        for (int kt = 0; kt < 2; kt++) {
            short8 a0 = *(const short8*)&h2w[(l15) * 72 + kt * 32 + quad * 8];
            short8 a1 = *(const short8*)&h2w[(l15 + 16) * 72 + kt * 32 + quad * 8];
#pragma unroll
            for (int nt = 0; nt < 8; nt++) {
                short8 bf = *(const short8*)&w3p[(l15 + 16 * nt) * 64 + kt * 32 + quad * 8];
                acc[0][nt] = __builtin_amdgcn_mfma_f32_16x16x32_bf16(a0, bf, acc[0][nt], 0, 0, 0);
                acc[1][nt] = __builtin_amdgcn_mfma_f32_16x16x32_bf16(a1, bf, acc[1][nt], 0, 0, 0);
            }
        }
#pragma unroll
        for (int nt = 0; nt < 8; nt++) {
            float m = acc[0][nt][0];
#pragma unroll
            for (int r = 1; r < 4; r++) m = fmaxf(m, acc[0][nt][r]);
#pragma unroll
            for (int r = 0; r < 4; r++) m = fmaxf(m, acc[1][nt][r]);
            // pool across quads (rows quad*4.. cover all 32 pts across 4 quads x 2 mt)
            m = fmaxf(m, __shfl_xor(m, 16));
            m = fmaxf(m, __shfl_xor(m, 32));
            m = fmaxf(m + b3v[nt], 0.0f);          // bias const over k: relu(max+b)
            if (lane < 16)
                out_np[((size_t)b * H3 + l15 + 16 * nt) * NP + s] = m;
        }
    }
}

extern "C" void kernel_launch(void* const* d_in, const int* in_sizes, int n_in,
                              void* d_out, int out_size, void* d_ws, size_t ws_size,
                              hipStream_t stream) {
    (void)in_sizes; (void)n_in; (void)out_size; (void)ws_size;
    const float* xyz = (const float*)d_in[0];
    const float* pts = (const float*)d_in[1];
    const float* W1  = (const float*)d_in[2];
    const float* b1  = (const float*)d_in[3];
    const float* W2  = (const float*)d_in[4];
    const float* b2  = (const float*)d_in[5];
    const float* W3  = (const float*)d_in[6];
    const float* b3  = (const float*)d_in[7];

    float* out    = (float*)d_out;
    float* newxyz = out;                       // (B, NP, 3)
    float* newpts = out + (size_t)BB * NP * 3; // (B, 128, NP)

    // workspace layout
    char* ws = (char*)d_ws;
    __hip_bfloat16* ptsT = (__hip_bfloat16*)ws;                               // 8 MB
    unsigned short* knni = (unsigned short*)(ws + (size_t)BB * NN * CP * 2);  // 1 MB
    short* w1p = (short*)(ws + 9437184);                                      // 64x96 bf16
    short* w2p = w1p + 64 * 96;                                               // 64x64
    short* w3p = w2p + 64 * 64;                                               // 128x64

    transpose_pts<<<dim3(NN / 64, BB), 256, 0, stream>>>(pts, ptsT);
    prep_weights <<<64, 256, 0, stream>>>(W1, W2, W3, w1p, w2p, w3p);
    fps_kernel   <<<BB, FPS_T, 0, stream>>>(xyz, newxyz);
    knn_kernel   <<<dim3(NP, BB), 256, 0, stream>>>(xyz, newxyz, knni);
    mlp_mfma     <<<dim3(BB * NP / 4), 256, 0, stream>>>(xyz, ptsT, knni,
                                                         w1p, w2p, w3p, b1, b2, b3, newpts);
}

// Round 5
// 1000.933 us; speedup vs baseline: 1.9371x; 1.0590x over previous
//
#include <hip/hip_runtime.h>
#include <hip/hip_bf16.h>
#include <stdint.h>
#include <string.h>

// Problem constants (fixed by setup_inputs).
#define BB   16
#define NN   4096
#define NP   1024
#define KK   32
#define CP   64
#define CIN  67    // 3 + 64
#define H3   128

typedef __attribute__((ext_vector_type(8))) short short8;
typedef __attribute__((ext_vector_type(4))) float floatx4;
typedef __attribute__((ext_vector_type(2))) float f32x2;

// ---------- exact-rounding helpers (match numpy op-by-op; no fma contraction) ----------
__device__ __forceinline__ float sq3_exact(float x, float y, float z) {
#pragma clang fp contract(off)
    float a = x * x;
    float b = y * y;
    float c = z * z;
    return (a + b) + c;
}
__device__ __forceinline__ float dot3_exact(float ax, float ay, float az,
                                            float bx, float by, float bz) {
#pragma clang fp contract(off)
    float a = ax * bx;
    float b = ay * by;
    float c = az * bz;
    return (a + b) + c;
}
__device__ __forceinline__ float d2_exact(float sn, float sx, float dt) {
#pragma clang fp contract(off)
    return (sn + sx) - 2.0f * dt;
}
__device__ __forceinline__ uint32_t f32_sortable(float f) {
    uint32_t u = __float_as_uint(f);
    return u ^ ((uint32_t)((int32_t)u >> 31) | 0x80000000u);
}
__device__ __forceinline__ unsigned long long umax64(unsigned long long a, unsigned long long b) {
    return a > b ? a : b;
}
__device__ __forceinline__ unsigned short bf16_bits(float f) {
    __hip_bfloat16 h = __float2bfloat16(f);
    unsigned short us;
    __builtin_memcpy(&us, &h, 2);
    return us;
}

// ---------- DPP wave64 u32-max reduce (VALU pipe; bound_ctrl=0 identity=0) ----------
template <int CTRL>
__device__ __forceinline__ uint32_t dpp_umax32_step(uint32_t k) {
    uint32_t o = (uint32_t)__builtin_amdgcn_update_dpp(0, (int)k, CTRL, 0xf, 0xf, true);
    return k > o ? k : o;
}
// returns the wave-wide max broadcast to all lanes (valid for keys where 0 is identity)
__device__ __forceinline__ uint32_t wave_umax32_dpp(uint32_t k) {
    k = dpp_umax32_step<0x111>(k);   // row_shr:1
    k = dpp_umax32_step<0x112>(k);   // row_shr:2
    k = dpp_umax32_step<0x114>(k);   // row_shr:4
    k = dpp_umax32_step<0x118>(k);   // row_shr:8
    k = dpp_umax32_step<0x142>(k);   // row_bcast:15
    k = dpp_umax32_step<0x143>(k);   // row_bcast:31
    return (uint32_t)__builtin_amdgcn_readlane((int)k, 63);
}

// ---------- kernel 1: transpose points (B,Cp,N) -> bf16 (B,N,Cp) ----------
__global__ void __launch_bounds__(256) transpose_pts(const float* __restrict__ pts,
                                                     __hip_bfloat16* __restrict__ ptsT) {
    __shared__ float tile[64][65];
    int b  = blockIdx.y;
    int n0 = blockIdx.x * 64;
    int tx = threadIdx.x & 63, ty = threadIdx.x >> 6;   // 64 x 4
    const float* src = pts + (size_t)b * CP * NN;
    for (int c = ty; c < 64; c += 4)
        tile[c][tx] = src[c * NN + n0 + tx];
    __syncthreads();
    __hip_bfloat16* dst = ptsT + ((size_t)b * NN + n0) * CP;
    for (int nn2 = ty; nn2 < 64; nn2 += 4)
        dst[nn2 * CP + tx] = __float2bfloat16(tile[tx][nn2]);
}

// ---------- kernel 1b: weights -> bf16, channel-reordered+padded ----------
__global__ void __launch_bounds__(256) prep_weights(const float* __restrict__ W1,
                                                    const float* __restrict__ W2,
                                                    const float* __restrict__ W3,
                                                    short* __restrict__ w1p,
                                                    short* __restrict__ w2p,
                                                    short* __restrict__ w3p) {
    int tid = blockIdx.x * 256 + threadIdx.x;
    int tot = gridDim.x * 256;
    for (int i = tid; i < 64 * 96; i += tot) {
        int o = i / 96, c = i % 96;
        float v = (c < 64) ? W1[o * CIN + 3 + c] : ((c < 67) ? W1[o * CIN + (c - 64)] : 0.0f);
        w1p[i] = (short)bf16_bits(v);
    }
    for (int i = tid; i < 64 * 64; i += tot)  w2p[i] = (short)bf16_bits(W2[i]);
    for (int i = tid; i < 128 * 64; i += tot) w3p[i] = (short)bf16_bits(W3[i]);
}

// ---------- kernel 2: FPS, one block per batch ----------
// 256 threads = 4 waves = 1/SIMD (VALU-issue-bound; 512thr regressed, R3).
// Update loop: packed v_pk_{add,mul}_f32 (separate mul/add = numpy-exact
// rounding), 2 points per packed op. Argmax reduce: u32 DPP max on raw float
// bits (nonneg => order-isomorphic) + ballot tie-break; rare exact path for
// cross-lane d-ties (u32-min over candidate n).
#define FPS_T 256

__global__ void __launch_bounds__(FPS_T, 1) fps_kernel(const float* __restrict__ xyz,
                                                       float* __restrict__ newxyz) {
    __shared__ __attribute__((aligned(16))) float4 sxyz[NN];   // 64 KB
    __shared__ int farr[NP];
    __shared__ __attribute__((aligned(16))) unsigned long long kbuf[2][4];
    int b = blockIdx.x;
    int tid = threadIdx.x;
    const float* xb = xyz + (size_t)b * NN * 3;
    f32x2 px2[8], py2[8], pz2[8], dm2[8];
#pragma unroll
    for (int jj = 0; jj < 8; jj++) {
        int n0 = jj * 512 + tid;
        int n1 = n0 + 256;
        float x0 = xb[n0 * 3 + 0], y0 = xb[n0 * 3 + 1], z0 = xb[n0 * 3 + 2];
        float x1 = xb[n1 * 3 + 0], y1 = xb[n1 * 3 + 1], z1 = xb[n1 * 3 + 2];
        px2[jj] = (f32x2){x0, x1}; py2[jj] = (f32x2){y0, y1}; pz2[jj] = (f32x2){z0, z1};
        sxyz[n0] = make_float4(x0, y0, z0, 0.0f);
        sxyz[n1] = make_float4(x1, y1, z1, 0.0f);
        dm2[jj] = (f32x2){1e10f, 1e10f};              // matches 10000000000.0 init
    }
#pragma unroll
    for (int jj = 0; jj < 8; jj++) {                  // pin to VGPRs: no LDS remat
        asm volatile("" : "+v"(px2[jj]), "+v"(py2[jj]), "+v"(pz2[jj]));
    }
    if (tid == 0) farr[0] = 0;                        // cents[0] = 0
    __syncthreads();
    int far = 0;
    for (int t = 0; t < NP - 1; t++) {
        float4 c = sxyz[far];                         // broadcast ds_read_b128
        f32x2 ccx = (f32x2){c.x, c.x};
        f32x2 ccy = (f32x2){c.y, c.y};
        f32x2 ccz = (f32x2){c.z, c.z};
        float bv = -1.0f; int bn = 0;
#pragma unroll
        for (int jj = 0; jj < 8; jj++) {
            f32x2 dx, dy, dz, xx, yy, zz, s01, s;
            asm("v_pk_add_f32 %0, %1, %2 neg_lo:[0,1] neg_hi:[0,1]" : "=v"(dx) : "v"(px2[jj]), "v"(ccx));
            asm("v_pk_add_f32 %0, %1, %2 neg_lo:[0,1] neg_hi:[0,1]" : "=v"(dy) : "v"(py2[jj]), "v"(ccy));
            asm("v_pk_add_f32 %0, %1, %2 neg_lo:[0,1] neg_hi:[0,1]" : "=v"(dz) : "v"(pz2[jj]), "v"(ccz));
            asm("v_pk_mul_f32 %0, %1, %1" : "=v"(xx) : "v"(dx));
            asm("v_pk_mul_f32 %0, %1, %1" : "=v"(yy) : "v"(dy));
            asm("v_pk_mul_f32 %0, %1, %1" : "=v"(zz) : "v"(dz));
            asm("v_pk_add_f32 %0, %1, %2" : "=v"(s01) : "v"(xx), "v"(yy));
            asm("v_pk_add_f32 %0, %1, %2" : "=v"(s)   : "v"(s01), "v"(zz));
            float d0 = fminf(dm2[jj].x, s.x);
            dm2[jj].x = d0;
            bn = (d0 > bv) ? (jj * 512 + tid) : bn;   // ascending n scan: ties -> smaller n
            bv = fmaxf(bv, d0);
            float d1 = fminf(dm2[jj].y, s.y);
            dm2[jj].y = d1;
            bn = (d1 > bv) ? (jj * 512 + 256 + tid) : bn;
            bv = fmaxf(bv, d1);
        }
        uint32_t bvb = __float_as_uint(bv);           // bv >= 0: bits order-isomorphic
        uint32_t m = wave_umax32_dpp(bvb);
        unsigned long long mask = __ballot(bvb == m);
        int n_sel;
        if (__popcll(mask) == 1) {
            n_sel = __builtin_amdgcn_readlane(bn, (int)(__ffsll((unsigned long long)mask) - 1));
        } else {                                      // rare: d-tie across lanes -> min n
            uint32_t cand = (bvb == m) ? (uint32_t)bn : 0xFFFFFFFFu;
            n_sel = (int)~wave_umax32_dpp(~cand);
        }
        int par = t & 1;
        if ((tid & 63) == 0)
            kbuf[par][tid >> 6] = ((unsigned long long)m << 32) | (unsigned)(NN - 1 - n_sel);
        __syncthreads();
        const ulonglong2* kp = (const ulonglong2*)kbuf[par];
        ulonglong2 k0 = kp[0], k1 = kp[1];
        unsigned long long mm = umax64(umax64(k0.x, k0.y), umax64(k1.x, k1.y));
        far = NN - 1 - (int)(unsigned)(mm & 0xFFFFFFFFull);
        if (tid == 0) farr[t + 1] = far;
    }
    __syncthreads();
    float* nxb = newxyz + (size_t)b * NP * 3;
    for (int t = tid; t < NP; t += FPS_T) {
        float4 p = sxyz[farr[t]];
        nxb[t * 3 + 0] = p.x;
        nxb[t * 3 + 1] = p.y;
        nxb[t * 3 + 2] = p.z;
    }
}

// ---------- kernel 3: exact kNN, barrier-free wave-local extraction ----------
// Wave w owns points [w*1024, (w+1)*1024), 16/lane, keys ck = ~sortable(d2)
// (u32; max-extract == min-d2, identity 0). 32 wave-local DPP rounds build a
// sorted top-32 list per wave; one barrier; exact rank-merge of 4 sorted
// lists via binary search (keys (d2,n) unique => ranks unique, top-32 exact).
__global__ void __launch_bounds__(256) knn_kernel(const float* __restrict__ xyz,
                                                  const float* __restrict__ newxyz,
                                                  unsigned short* __restrict__ knn_out) {
    __shared__ unsigned long long lists[4][32];
    int s = blockIdx.x, b = blockIdx.y, tid = threadIdx.x;
    int wave = tid >> 6, lane = tid & 63;
    const float* c3 = newxyz + ((size_t)b * NP + s) * 3;
    float cx = c3[0], cy = c3[1], cz = c3[2];
    float sn = sq3_exact(cx, cy, cz);
    const float* xb = xyz + (size_t)b * NN * 3;
    uint32_t ck[16];
    uint32_t best = 0; int bj = 0;
#pragma unroll
    for (int j = 0; j < 16; j++) {
        int n = wave * 1024 + j * 64 + lane;
        float x = xb[n * 3 + 0], y = xb[n * 3 + 1], z = xb[n * 3 + 2];
        float sx = sq3_exact(x, y, z);
        float dt = dot3_exact(cx, cy, cz, x, y, z);
        float d2 = d2_exact(sn, sx, dt);
        uint32_t c = ~f32_sortable(d2);
        ck[j] = c;
        if (c > best) { best = c; bj = j; }           // ascending j: ties -> smaller n
    }
    for (int r = 0; r < KK; r++) {
        uint32_t m = wave_umax32_dpp(best);
        unsigned long long mask = __ballot(best == m);
        int n_loc;                                    // wave-local n = bj*64+lane
        if (__popcll(mask) == 1) {
            int myn = (bj << 6) | lane;
            n_loc = __builtin_amdgcn_readlane(myn, (int)(__ffsll((unsigned long long)mask) - 1));
        } else {                                      // rare: d2-tie across lanes -> min n
            uint32_t cand = (best == m) ? (uint32_t)((bj << 6) | lane) : 0xFFFFFFFFu;
            n_loc = (int)~wave_umax32_dpp(~cand);
        }
        if (lane == 0)
            lists[wave][r] = ((unsigned long long)(~m) << 32) | (unsigned)(wave * 1024 + n_loc);
        if ((n_loc & 63) == lane) {                   // owner consumes + rescans
            ck[n_loc >> 6] = 0;
            best = 0; bj = 0;
#pragma unroll
            for (int j = 0; j < 16; j++)
                if (ck[j] > best) { best = ck[j]; bj = j; }
        }
    }
    __syncthreads();
    if (tid < 128) {                                  // exact rank-merge of 4 sorted lists
        int w = tid >> 5, i = tid & 31;
        unsigned long long key = lists[w][i];
        int rank = i;
#pragma unroll
        for (int w2 = 0; w2 < 4; w2++) {
            if (w2 == w) continue;
            int pos = 0;
#pragma unroll
            for (int stp = 16; stp >= 1; stp >>= 1)
                if (lists[w2][pos + stp - 1] < key) pos += stp;
            rank += pos;
        }
        if (rank < KK)
            knn_out[((size_t)b * NP + s) * KK + rank] = (unsigned short)(key & 0xFFFFull);
    }
}

// ---------- kernel 4: gather + 3-layer MLP via bf16 MFMA + maxpool ----------
__global__ void __launch_bounds__(256) mlp_mfma(const float* __restrict__ xyz,
                                                const __hip_bfloat16* __restrict__ ptsT,
                                                const unsigned short* __restrict__ knni,
                                                const short* __restrict__ w1p,
                                                const short* __restrict__ w2p,
                                                const short* __restrict__ w3p,
                                                const float* __restrict__ b1,
                                                const float* __restrict__ b2,
                                                const float* __restrict__ b3,
                                                float* __restrict__ out_np) {
    __shared__ __attribute__((aligned(16))) short lds[4 * 7680];   // 60 KB
    int tid  = threadIdx.x;
    int wave = tid >> 6, lane = tid & 63;
    int l15  = lane & 15, quad = lane >> 4;
    int gid  = blockIdx.x * 4 + wave;            // task = (b,s)
    int b    = gid >> 10, s = gid & (NP - 1);
    short* Gw  = lds + wave * 7680;              // 32 rows x 96
    short* h1w = Gw + 32 * 96;                   // 32 rows x 72
    short* h2w = h1w + 32 * 72;                  // 32 rows x 72

    float b1v[4], b2v[4], b3v[8];
#pragma unroll
    for (int i = 0; i < 4; i++) b1v[i] = b1[l15 + 16 * i];
#pragma unroll
    for (int i = 0; i < 4; i++) b2v[i] = b2[l15 + 16 * i];
#pragma unroll
    for (int i = 0; i < 8; i++) b3v[i] = b3[l15 + 16 * i];

    {   // gather: 32 neighbors -> G rows (2 lanes per row)
        int r = lane & 31, h = lane >> 5;
        int n = (int)knni[(size_t)gid * KK + r];
        const short8* prow = (const short8*)(ptsT + ((size_t)b * NN + n) * CP);
        short8 c0 = prow[h * 4 + 0], c1 = prow[h * 4 + 1];
        short8 c2 = prow[h * 4 + 2], c3 = prow[h * 4 + 3];
        short8* gdst = (short8*)&Gw[r * 96];
        gdst[h * 4 + 0] = c0; gdst[h * 4 + 1] = c1;
        gdst[h * 4 + 2] = c2; gdst[h * 4 + 3] = c3;
        short8 z8 = {0, 0, 0, 0, 0, 0, 0, 0};
        if (h == 0) {
            const float* xp = xyz + ((size_t)b * NN + n) * 3;
            short8 v = z8;
            v[0] = (short)bf16_bits(xp[0]);
            v[1] = (short)bf16_bits(xp[1]);
            v[2] = (short)bf16_bits(xp[2]);
            gdst[8] = v; gdst[9] = z8;
        } else {
            gdst[10] = z8; gdst[11] = z8;
        }
    }

    {   // layer 1: G(32x96) x W1p^T -> h1(32x64)
        floatx4 acc[2][4];
#pragma unroll
        for (int mt = 0; mt < 2; mt++)
#pragma unroll
            for (int nt = 0; nt < 4; nt++) acc[mt][nt] = (floatx4)0.0f;
#pragma unroll
        for (int kt = 0; kt < 3; kt++) {
            short8 a0 = *(const short8*)&Gw[(l15) * 96 + kt * 32 + quad * 8];
            short8 a1 = *(const short8*)&Gw[(l15 + 16) * 96 + kt * 32 + quad * 8];
#pragma unroll
            for (int nt = 0; nt < 4; nt++) {
                short8 bf = *(const short8*)&w1p[(l15 + 16 * nt) * 96 + kt * 32 + quad * 8];
                acc[0][nt] = __builtin_amdgcn_mfma_f32_16x16x32_bf16(a0, bf, acc[0][nt], 0, 0, 0);
                acc[1][nt] = __builtin_amdgcn_mfma_f32_16x16x32_bf16(a1, bf, acc[1][nt], 0, 0, 0);
            }
        }
#pragma unroll
        for (int mt = 0; mt < 2; mt++)
#pragma unroll
            for (int nt = 0; nt < 4; nt++)
#pragma unroll
                for (int r = 0; r < 4; r++) {
                    float v = fmaxf(acc[mt][nt][r] + b1v[nt], 0.0f);
                    h1w[(quad * 4 + r + 16 * mt) * 72 + l15 + 16 * nt] = (short)bf16_bits(v);
                }
    }

    {   // layer 2: h1(32x64) x W2^T -> h2(32x64)
        floatx4 acc[2][4];
#pragma unroll
        for (int mt = 0; mt < 2; mt++)
#pragma unroll
            for (int nt = 0; nt < 4; nt++) acc[mt][nt] = (floatx4)0.0f;
#pragma unroll
        for (int kt = 0; kt < 2; kt++) {
            short8 a0 = *(const short8*)&h1w[(l15) * 72 + kt * 32 + quad * 8];
            short8 a1 = *(const short8*)&h1w[(l15 + 16) * 72 + kt * 32 + quad * 8];
#pragma unroll
            for (int nt = 0; nt < 4; nt++) {
                short8 bf = *(const short8*)&w2p[(l15 + 16 * nt) * 64 + kt * 32 + quad * 8];
                acc[0][nt] = __builtin_amdgcn_mfma_f32_16x16x32_bf16(a0, bf, acc[0][nt], 0, 0, 0);
                acc[1][nt] = __builtin_amdgcn_mfma_f32_16x16x32_bf16(a1, bf, acc[1][nt], 0, 0, 0);
            }
        }
#pragma unroll
        for (int mt = 0; mt < 2; mt++)
#pragma unroll
            for (int nt = 0; nt < 4; nt++)
#pragma unroll
                for (int r = 0; r < 4; r++) {
                    float v = fmaxf(acc[mt][nt][r] + b2v[nt], 0.0f);
                    h2w[(quad * 4 + r + 16 * mt) * 72 + l15 + 16 * nt] = (short)bf16_bits(v);
                }
    }

    {   // layer 3: h2(32x64) x W3^T -> (32x128), fused maxpool over 32 pts
        floatx4 acc[2][8];
#pragma unroll
        for (int mt = 0; mt < 2; mt++)
#pragma unroll
            for (int nt = 0; nt < 8; nt++) acc[mt][nt] = (floatx4)0.0f;
#pragma unroll
        for (int kt = 0; kt < 2; kt++) {
            short8 a0 = *(const short8*)&h2w[(l15) * 72 + kt * 32 + quad * 8];
            short8 a1 = *(const short8*)&h2w[(l15 + 16) * 72 + kt * 32 + quad * 8];
#pragma unroll
            for (int nt = 0; nt < 8; nt++) {
                short8 bf = *(const short8*)&w3p[(l15 + 16 * nt) * 64 + kt * 32 + quad * 8];
                acc[0][nt] = __builtin_amdgcn_mfma_f32_16x16x32_bf16(a0, bf, acc[0][nt], 0, 0, 0);
                acc[1][nt] = __builtin_amdgcn_mfma_f32_16x16x32_bf16(a1, bf, acc[1][nt], 0, 0, 0);
            }
        }
#pragma unroll
        for (int nt = 0; nt < 8; nt++) {
            float m = acc[0][nt][0];
#pragma unroll
            for (int r = 1; r < 4; r++) m = fmaxf(m, acc[0][nt][r]);
#pragma unroll
            for (int r = 0; r < 4; r++) m = fmaxf(m, acc[1][nt][r]);
            m = fmaxf(m, __shfl_xor(m, 16));
            m = fmaxf(m, __shfl_xor(m, 32));
            m = fmaxf(m + b3v[nt], 0.0f);
            if (lane < 16)
                out_np[((size_t)b * H3 + l15 + 16 * nt) * NP + s] = m;
        }
    }
}

extern "C" void kernel_launch(void* const* d_in, const int* in_sizes, int n_in,
                              void* d_out, int out_size, void* d_ws, size_t ws_size,
                              hipStream_t stream) {
    (void)in_sizes; (void)n_in; (void)out_size; (void)ws_size;
    const float* xyz = (const float*)d_in[0];
    const float* pts = (const float*)d_in[1];
    const float* W1  = (const float*)d_in[2];
    const float* b1  = (const float*)d_in[3];
    const float* W2  = (const float*)d_in[4];
    const float* b2  = (const float*)d_in[5];
    const float* W3  = (const float*)d_in[6];
    const float* b3  = (const float*)d_in[7];

    float* out    = (float*)d_out;
    float* newxyz = out;                       // (B, NP, 3)
    float* newpts = out + (size_t)BB * NP * 3; // (B, 128, NP)

    char* ws = (char*)d_ws;
    __hip_bfloat16* ptsT = (__hip_bfloat16*)ws;                               // 8 MB
    unsigned short* knni = (unsigned short*)(ws + (size_t)BB * NN * CP * 2);  // 1 MB
    short* w1p = (short*)(ws + 9437184);
    short* w2p = w1p + 64 * 96;
    short* w3p = w2p + 64 * 64;

    transpose_pts<<<dim3(NN / 64, BB), 256, 0, stream>>>(pts, ptsT);
    prep_weights <<<64, 256, 0, stream>>>(W1, W2, W3, w1p, w2p, w3p);
    fps_kernel   <<<BB, FPS_T, 0, stream>>>(xyz, newxyz);
    knn_kernel   <<<dim3(NP, BB), 256, 0, stream>>>(xyz, newxyz, knni);
    mlp_mfma     <<<dim3(BB * NP / 4), 256, 0, stream>>>(xyz, ptsT, knni,
                                                         w1p, w2p, w3p, b1, b2, b3, newpts);
}